// Round 14
// baseline (1052.777 us; speedup 1.0000x reference)
//
#include <hip/hip_runtime.h>

typedef unsigned short u16;
typedef unsigned int u32;
typedef unsigned long long u64;
typedef __bf16 bf16x8 __attribute__((ext_vector_type(8)));
typedef float f32x4 __attribute__((ext_vector_type(4)));
typedef u16 u16x8 __attribute__((ext_vector_type(8)));
typedef u16 u16x4 __attribute__((ext_vector_type(4)));
typedef u32 u32x4 __attribute__((ext_vector_type(4)));

#define MFMA16x16(a,b,c) __builtin_amdgcn_mfma_f32_16x16x32_bf16((a),(b),(c),0,0,0)

static __device__ __forceinline__ u16 f2bf(float f){
  u32 u = __builtin_bit_cast(u32, f);
  u += 0x7fffu + ((u >> 16) & 1u);
  return (u16)(u >> 16);
}
static __device__ __forceinline__ float bf2f(u16 h){
  u32 u = ((u32)h) << 16;
  return __builtin_bit_cast(float, u);
}
static __device__ __forceinline__ float fast_sigmoid(float x){
  return 1.f / (1.f + __expf(-x));
}
static __device__ __forceinline__ float fast_tanh(float x){
  float e = __expf(2.f * x);
  return 1.f - 2.f / (e + 1.f);
}
static __device__ __forceinline__ float fast_softplus(float x){
  return (x > 15.f) ? x : __logf(1.f + __expf(x));
}
static __device__ __forceinline__ f32x4 zero4(){
  f32x4 v; v[0]=0.f; v[1]=0.f; v[2]=0.f; v[3]=0.f; return v;
}
static __device__ __forceinline__ f32x4 splat4(float x){
  f32x4 v; v[0]=x; v[1]=x; v[2]=x; v[3]=x; return v;
}

// ---------------------------------------------------------------------------
// Weight swizzle into MFMA B-fragment order:
// dst[ks][nt][lane][j] = W[k = ks*32 + (lane>>4)*8 + j][ncol = nt*16 + (lane&15)]
// modes: 0 GRU hidden  2 post(500x500+b)  3 zW  4 heads  5 enc Wih
// ---------------------------------------------------------------------------
static __device__ __forceinline__ void build_one(
    u16* __restrict__ dst, int mode, int NT, int idx,
    const float* __restrict__ W0, const float* __restrict__ b0,
    const float* __restrict__ W1, const float* __restrict__ b1)
{
  int j    = idx & 7;
  int lane = (idx >> 3) & 63;
  int ntks = idx >> 9;
  int nt   = ntks % NT;
  int ks   = ntks / NT;
  int k    = ks * 32 + ((lane >> 4) << 3) + j;
  int ncol = (nt << 4) + (lane & 15);
  float v = 0.f;
  if (mode == 0){                         // GRU hidden: rows 0..499 Whh^T, 511 bhh
    int g = ncol >> 9;
    int jin = ncol & 511;
    if (jin < 500){
      int row = g * 500 + jin;
      if (k < 500) v = W0[row * 500 + k];
      else if (k == 511) v = b0[row];
    }
  } else if (mode == 2){                  // post: W0 [500][500], bias row 511
    if (ncol < 500){
      if (k < 500) v = W0[ncol * 500 + k];
      else if (k == 511) v = b0[ncol];
    }
  } else if (mode == 3){                  // zW: cols 0..2 zm (W0 [3][503]), 3..5 zs
    int c = ncol;
    if (c < 3){
      if (k < 500) v = W0[c * 503 + k];
      else if (k == 511) v = b0[c];
    } else if (c < 6){
      int cc = c - 3;
      if (k < 500) v = W1[cc * 503 + k];
      else if (k == 511) v = b1[cc];
    }
  } else if (mode == 4){                  // heads: cols 0..47 xm (<38), 48..95 xs
    int grp = ncol / 48;
    int cc  = ncol - grp * 48;
    if (grp < 2 && cc < 38){
      const float* W  = grp ? W1 : W0;
      const float* bb = grp ? b1 : b0;
      if (k < 500) v = W[cc * 500 + k];
      else if (k == 511) v = bb[cc];
    }
  } else {                                // mode 5: enc Wih [1500][38]
    int g = ncol >> 9;
    int jin = ncol & 511;
    if (jin < 500 && k < 38) v = W0[(g * 500 + jin) * 38 + k];
  }
  dst[idx] = f2bf(v);
}

// One launch for all weight prep + flow params + counter zeroing.
__global__ void build_all(
    u16* ENCF, u16* DECF, u16* EGIF, u16* PF0, u16* PF1, u16* PF2, u16* PF3,
    u16* ZFR, u16* HFR, float* FPP, u32* CNT,
    const float* enc_Whh, const float* enc_bhh, const float* enc_Wih,
    const float* dec_Whh, const float* dec_bhh,
    const float* enc_W1, const float* enc_b1, const float* enc_W2, const float* enc_b2,
    const float* dec_W1, const float* dec_b1, const float* dec_W2, const float* dec_b2,
    const float* zm_W, const float* zm_b, const float* zs_W, const float* zs_b,
    const float* xm_W, const float* xm_b, const float* xs_W, const float* xs_b,
    const float* flow_w, const float* flow_b, const float* flow_u)
{
  const int b = blockIdx.x, tid = threadIdx.x;
  if      (b < 3072)  build_one(ENCF,0,96,(b       )*256+tid, enc_Whh,enc_bhh,0,0);
  else if (b < 6144)  build_one(DECF,0,96,(b- 3072 )*256+tid, dec_Whh,dec_bhh,0,0);
  else if (b < 6528)  build_one(EGIF,5,96,(b- 6144 )*256+tid, enc_Wih,0,0,0);
  else if (b < 7552)  build_one(PF0 ,2,32,(b- 6528 )*256+tid, enc_W1,enc_b1,0,0);
  else if (b < 8576)  build_one(PF1 ,2,32,(b- 7552 )*256+tid, enc_W2,enc_b2,0,0);
  else if (b < 9600)  build_one(PF2 ,2,32,(b- 8576 )*256+tid, dec_W1,dec_b1,0,0);
  else if (b < 10624) build_one(PF3 ,2,32,(b- 9600 )*256+tid, dec_W2,dec_b2,0,0);
  else if (b < 10656) build_one(ZFR ,3, 1,(b-10624 )*256+tid, zm_W,zm_b,zs_W,zs_b);
  else if (b < 10848) build_one(HFR ,4, 6,(b-10656 )*256+tid, xm_W,xm_b,xs_W,xs_b);
  else if (b == 10848){
    if (tid < 20){
      int l = tid;
      float w0 = flow_w[l*3+0], w1 = flow_w[l*3+1], w2 = flow_w[l*3+2];
      float u0 = flow_u[l*3+0], u1 = flow_u[l*3+1], u2 = flow_u[l*3+2];
      float wu = w0*u0 + w1*u1 + w2*u2;
      float m  = -1.f + fast_softplus(wu);
      float ww = w0*w0 + w1*w1 + w2*w2 + 1e-7f;
      float sc = (m - wu) / ww;
      float uh0 = u0 + sc*w0, uh1 = u1 + sc*w1, uh2 = u2 + sc*w2;
      float uw  = uh0*w0 + uh1*w1 + uh2*w2;
      FPP[l*8+0]=w0; FPP[l*8+1]=w1; FPP[l*8+2]=w2; FPP[l*8+3]=flow_b[l];
      FPP[l*8+4]=uh0; FPP[l*8+5]=uh1; FPP[l*8+6]=uh2; FPP[l*8+7]=uw;
    }
  } else {
    for (int i = tid; i < 8192; i += 256) CNT[i] = 0;   // enc+dec counter arrays
  }
}

// ---------------------------------------------------------------------------
// GRU v18 = v14 (R8/R9-proven 316/307 us) + PER-WAVE DETECT (B1 removed).
// Residency arc closed after two nulls (R12 post-loop pins, R13 "+v" opaque
// pins; VGPR 164 both): weights are evidently AGPR-resident already
// (unified file; rocprof VGPR_Count excludes AGPRs) — step time is the
// counter-sync chain at observed fabric latency. v18's single change:
// each wave's lane 0 spins on the counter itself (lanes of a wave share a
// PC -> wave reconverges after the predicated spin), then the wave issues
// its stage loads directly. Removes B1 (detect-broadcast barrier) and the
// tid0->waves skew. Poll traffic 256->1024 pollers chip-wide (4x; far
// below R1's congestion regime). LDS hazards: stage writes touch only
// remote-slice rows (B2-covered); epilogue own-slice writes precede B4;
// hout drains during the >=RT-long spin. Protocol ledger: tagged R1-R3,
// XCD-L2 R6, K-split R11 all measured worse; counters stand.
// Barriers/step: B2 stage done, B3 mfma reads done, B4 vmcnt drain -> signal.
// ---------------------------------------------------------------------------
__global__ __launch_bounds__(256, 1) void gru8_kernel(
    const u16* __restrict__ frag, const u16* __restrict__ giw,
    const float* __restrict__ xsrc, const u64* __restrict__ zsrc,
    const float* __restrict__ Wih3, const float* __restrict__ bih3,
    u32* __restrict__ hbufbase, u16* __restrict__ hout, u32* __restrict__ cntbase)
{
  __shared__ u32 hstage[20800];             // rows 0..15, stride 260; tail = ballast
  __shared__ u16 xstage[1280];              // [2 slots][16 rows][40] (pads 38,39 = 0)
  const int tid  = threadIdx.x, lane = tid & 63;
  const int wv   = tid >> 6;                // 0..3
  const int q    = lane >> 4, c = lane & 15;
  const int gid  = blockIdx.x & 31, s = blockIdx.x >> 5;   // s = 0..7
  const int b0   = gid * 16;
  const int nt0  = s*4 + wv;                // 0..31
  const int col  = nt0*16 + c;
  u32* cnt = cntbase + gid * 128;           // 512 B stride
  u32* hb  = hbufbase + (size_t)gid * 8192; // 2 bufs x 16x256 u32
  const bool enc = (giw != nullptr);

  // --- hidden weights into VGPRs/AGPRs: 3 gates x 16 ks (held all steps) ---
  u16x8 wf[3][16];
  #pragma unroll
  for (int ks = 0; ks < 16; ++ks)
    #pragma unroll
    for (int g = 0; g < 3; ++g)
      wf[g][ks] = *(const u16x8*)(frag + (((size_t)ks*96 + g*32 + nt0)*64 + lane)*8);

  // --- encoder: Wih B-frags (2 ks x 3 gates) + per-thread biases +
  //     cooperative x-staging geometry (3 (row,k) pairs, constant over t) ---
  u16x8 wih[2][3];
  float bs0 = 0.f, bs1 = 0.f, bs2 = 0.f;
  int xr0=0, xk0=0, xr1=0, xk1=0, xr2=0, xk2=0;
  if (enc){
    #pragma unroll
    for (int ks = 0; ks < 2; ++ks)
      #pragma unroll
      for (int g = 0; g < 3; ++g)
        wih[ks][g] = *(const u16x8*)(giw + (((size_t)ks*96 + g*32 + nt0)*64 + lane)*8);
    if (col < 500){
      bs0 = bih3[col]; bs1 = bih3[500 + col]; bs2 = bih3[1000 + col];
    }
    xr0 = tid / 38;         xk0 = tid - xr0*38;          // e = tid       (0..255)
    int e1 = tid + 256;     xr1 = e1 / 38; xk1 = e1 - xr1*38;   // 256..511
    if (tid < 96){ int e2 = tid + 512; xr2 = e2 / 38; xk2 = e2 - xr2*38; } // 512..607
  }

  // --- decoder-mode per-lane gi weights (z is rank 3) ---
  float wz[3][3] = {{0,0,0},{0,0,0},{0,0,0}}, wb[3] = {0,0,0};
  if (!enc && col < 500){
    #pragma unroll
    for (int g = 0; g < 3; ++g){
      #pragma unroll
      for (int k = 0; k < 3; ++k) wz[g][k] = Wih3[(g*500 + col)*3 + k];
      wb[g] = bih3[g*500 + col];
    }
  }

  // --- staging geometry: thread stages 1 u64 per remote slice ---
  const int srow = tid >> 4;                // 0..15
  const int spos = (tid & 15) * 2;          // u32 offset within 32-u32 slice row

  float hold[4] = {0.f, 0.f, 0.f, 0.f};
  u64 zv[4];
  float xf0 = 0.f, xf1 = 0.f, xf2 = 0.f;    // next-step x floats (enc)
  {
    // h0 = 0 (+ col511 = 1.0): own LDS copy + IF copy for remote blocks
    u32 me = (col == 511) ? 0x3F80u : 0u;
    u32 pr = __shfl_xor(me, 1, 64);
    if (!(c & 1)){
      u32 val = me | (pr << 16);
      #pragma unroll
      for (int r = 0; r < 4; ++r){
        hstage[(q*4+r)*260 + (col>>1)] = val;
        __hip_atomic_store(hb + (q*4+r)*256 + (col>>1), val,
                           __ATOMIC_RELAXED, __HIP_MEMORY_SCOPE_AGENT);
      }
    }
    // prime inputs for t=0
    if (enc){
      // zero pad columns 38,39 of both slots
      if (tid < 64){
        int slot = tid >> 5, r = tid & 15, p = (tid >> 4) & 1;
        xstage[slot*640 + r*40 + 38 + p] = 0;
      }
      float v0 = xsrc[((size_t)(b0 + xr0)*100 + 0)*38 + xk0];
      float v1 = xsrc[((size_t)(b0 + xr1)*100 + 0)*38 + xk1];
      xstage[xr0*40 + xk0] = f2bf(v0);
      xstage[xr1*40 + xk1] = f2bf(v1);
      if (tid < 96){
        float v2 = xsrc[((size_t)(b0 + xr2)*100 + 0)*38 + xk2];
        xstage[xr2*40 + xk2] = f2bf(v2);
      }
    } else {
      #pragma unroll
      for (int r = 0; r < 4; ++r)
        zv[r] = zsrc[(size_t)(b0 + q*4 + r)*100 + 0];
    }
  }
  __syncthreads();                          // drains vmcnt(0): h0 stores acked at IF
  if (tid == 0)
    __hip_atomic_fetch_add(cnt, 1u, __ATOMIC_RELAXED, __HIP_MEMORY_SCOPE_AGENT);

  #pragma unroll 1
  for (int t = 0; t < 100; ++t){
    // --- per-wave detect: lane 0 spins; wave reconverges (no B1 barrier) ---
    if (lane == 0){
      const u32 target = 8u*(u32)(t+1);
      int guard = 0;
      while (__hip_atomic_load(cnt, __ATOMIC_RELAXED, __HIP_MEMORY_SCOPE_AGENT) < target){
        if (++guard > (1<<24)) break;       // hang-breaker
      }
    }

    // --- stage 7 remote slices (overlapped u64 loads -> 1 RT) ---
    {
      const u64* src = (const u64*)(hb + (t & 1)*4096);
      u64 sv[7];
      #pragma unroll
      for (int r = 0; r < 7; ++r){
        const int rs = (s + 1 + r) & 7;
        sv[r] = __hip_atomic_load(src + srow*128 + rs*16 + (tid & 15),
                                  __ATOMIC_RELAXED, __HIP_MEMORY_SCOPE_AGENT);
      }
      // issue next-step x loads (coalesced; consumed in epilogue -> RT hidden)
      if (enc && t < 99){
        xf0 = xsrc[((size_t)(b0 + xr0)*100 + (t+1))*38 + xk0];
        xf1 = xsrc[((size_t)(b0 + xr1)*100 + (t+1))*38 + xk1];
        if (tid < 96) xf2 = xsrc[((size_t)(b0 + xr2)*100 + (t+1))*38 + xk2];
      }
      #pragma unroll
      for (int r = 0; r < 7; ++r){
        const int rs = (s + 1 + r) & 7;
        *(u64*)&hstage[srow*260 + rs*32 + spos] = sv[r];
      }
    }
    __syncthreads();                        // B2: full h_t tile in LDS

    // --- accumulators: enc seeds r/z/n with fused gi (A-frags from LDS) ---
    f32x4 acc0, acc1, acc2, gN;
    if (enc){
      const int slot = t & 1;
      bf16x8 ax0 = *(const bf16x8*)&xstage[slot*640 + c*40 + q*8];
      u16x8 z8 = {0,0,0,0,0,0,0,0};
      bf16x8 ax1 = __builtin_bit_cast(bf16x8, z8);
      if (q == 0) ax1 = *(const bf16x8*)&xstage[slot*640 + c*40 + 32];
      acc0 = splat4(bs0);
      acc0 = MFMA16x16(ax0, __builtin_bit_cast(bf16x8, wih[0][0]), acc0);
      acc0 = MFMA16x16(ax1, __builtin_bit_cast(bf16x8, wih[1][0]), acc0);
      acc1 = splat4(bs1);
      acc1 = MFMA16x16(ax0, __builtin_bit_cast(bf16x8, wih[0][1]), acc1);
      acc1 = MFMA16x16(ax1, __builtin_bit_cast(bf16x8, wih[1][1]), acc1);
      gN   = splat4(bs2);
      gN   = MFMA16x16(ax0, __builtin_bit_cast(bf16x8, wih[0][2]), gN);
      gN   = MFMA16x16(ax1, __builtin_bit_cast(bf16x8, wih[1][2]), gN);
      acc2 = zero4();
    } else {
      acc0 = zero4(); acc1 = zero4(); acc2 = zero4(); gN = zero4();
    }
    #pragma unroll
    for (int ks = 0; ks < 16; ++ks){
      bf16x8 af = *(const bf16x8*)&hstage[c*260 + ks*16 + q*4];
      acc0 = MFMA16x16(af, __builtin_bit_cast(bf16x8, wf[0][ks]), acc0);
      acc1 = MFMA16x16(af, __builtin_bit_cast(bf16x8, wf[1][ks]), acc1);
      acc2 = MFMA16x16(af, __builtin_bit_cast(bf16x8, wf[2][ks]), acc2);
    }
    __syncthreads();                        // B3: all mfma LDS reads done

    // --- epilogue: write next x tile to LDS (visible after B4) ---
    if (enc && t < 99){
      const int ns = (t+1) & 1;
      xstage[ns*640 + xr0*40 + xk0] = f2bf(xf0);
      xstage[ns*640 + xr1*40 + xk1] = f2bf(xf1);
      if (tid < 96) xstage[ns*640 + xr2*40 + xk2] = f2bf(xf2);
    }

    u16 hvv[4];
    u32* nxt = hb + ((t+1) & 1)*4096;
    {
      #pragma unroll
      for (int r = 0; r < 4; ++r){
        float ar, az, gn;
        if (enc){
          ar = acc0[r]; az = acc1[r]; gn = gN[r];
        } else {
          float z0 = bf2f((u16)(zv[r]));
          float z1 = bf2f((u16)(zv[r] >> 16));
          float z2 = bf2f((u16)(zv[r] >> 32));
          ar = acc0[r] + z0*wz[0][0] + z1*wz[0][1] + z2*wz[0][2] + wb[0];
          az = acc1[r] + z0*wz[1][0] + z1*wz[1][1] + z2*wz[1][2] + wb[1];
          gn = z0*wz[2][0] + z1*wz[2][1] + z2*wz[2][2] + wb[2];
        }
        float an = acc2[r];
        float rr = fast_sigmoid(ar);
        float zz = fast_sigmoid(az);
        float nn = fast_tanh(gn + rr*an);
        float h  = (1.f - zz)*nn + zz*hold[r];
        hold[r] = h;
        u16 hv16 = (col < 500) ? f2bf(h) : ((col == 511) ? (u16)0x3F80 : (u16)0);
        hvv[r] = hv16;
        u32 me = hv16;
        u32 pr = __shfl_xor(me, 1, 64);
        if (!(c & 1)){
          u32 val = me | (pr << 16);
          hstage[(q*4+r)*260 + (col>>1)] = val;     // own slice -> LDS for t+1
          __hip_atomic_store(nxt + (q*4+r)*256 + (col>>1), val,
                             __ATOMIC_RELAXED, __HIP_MEMORY_SCOPE_AGENT);
        }
      }
    }
    __syncthreads();                        // B4: drains vmcnt -> stores at IF
    if (tid == 0)
      __hip_atomic_fetch_add(cnt, 1u, __ATOMIC_RELAXED, __HIP_MEMORY_SCOPE_AGENT);
    // off-critical-path: hout + next-input prefetch (dec)
    #pragma unroll
    for (int r = 0; r < 4; ++r)
      __builtin_nontemporal_store(hvv[r],
          hout + ((size_t)(b0 + q*4 + r)*100 + t)*512 + col);
    if (!enc && t < 99){
      #pragma unroll
      for (int r = 0; r < 4; ++r)
        zv[r] = zsrc[(size_t)(b0 + q*4 + r)*100 + (t+1)];
    }
  }
}

// ---------------------------------------------------------------------------
// Fused post-net chain v2 (unchanged from R9 — proven): B-frag register
// reuse via nt-quarter wave mapping; bit-exact vs v1.
// mode 0: hmT[t][512][8] = P2 @ ZFR   mode 1: heads (mu, softplus std).
// ---------------------------------------------------------------------------
__global__ __launch_bounds__(512, 4) void post_chain(
    const u16* __restrict__ A, const u16* __restrict__ fA,
    const u16* __restrict__ fB, const u16* __restrict__ f3,
    float* __restrict__ o0, float* __restrict__ o1, int mode)
{
  __shared__ u16 AS[32768];                 // [rt4][ks16][qq4][m16][j8]
  const int tid = threadIdx.x, lane = tid & 63, w = tid >> 6;
  const int q = lane >> 4, c = lane & 15;
  const size_t rowbase = (size_t)blockIdx.x * 64;

  // ---- stage 1: wave owns nt = w*4..w*4+3, loops all 4 row-tiles ----
  f32x4 acc[4][4];                          // [rt][i]
  #pragma unroll
  for (int rt = 0; rt < 4; ++rt)
    #pragma unroll
    for (int i = 0; i < 4; ++i) acc[rt][i] = zero4();
  #pragma unroll 1
  for (int ks = 0; ks < 16; ++ks){
    bf16x8 bfr[4];
    #pragma unroll
    for (int i = 0; i < 4; ++i){
      const int nt = w*4 + i;
      bfr[i] = __builtin_bit_cast(bf16x8,
          *(const u16x8*)(fA + (((size_t)ks * 32 + nt) * 64 + lane) * 8));
    }
    #pragma unroll
    for (int rt = 0; rt < 4; ++rt){
      bf16x8 af = __builtin_bit_cast(bf16x8,
          *(const u16x8*)(A + (rowbase + rt*16 + c) * 512 + ks * 32 + q * 8));
      #pragma unroll
      for (int i = 0; i < 4; ++i)
        acc[rt][i] = MFMA16x16(af, bfr[i], acc[rt][i]);
    }
  }
  #pragma unroll
  for (int rt = 0; rt < 4; ++rt)
    #pragma unroll
    for (int i = 0; i < 4; ++i){
      const int cl = (w*4 + i)*16 + c;
      const int ks2 = cl >> 5, qq = (cl >> 3) & 3, j = cl & 7;
      #pragma unroll
      for (int r = 0; r < 4; ++r){
        const int m = q*4 + r;
        float v = acc[rt][i][r];
        v = fmaxf(v, 0.1f * v);
        AS[(((rt*16 + ks2)*4 + qq)*16 + m)*8 + j] =
            (cl < 500) ? f2bf(v) : ((cl == 511) ? (u16)0x3F80 : (u16)0);
      }
    }
  __syncthreads();

  // ---- stage 2: same mapping, A from LDS ----
  #pragma unroll
  for (int rt = 0; rt < 4; ++rt)
    #pragma unroll
    for (int i = 0; i < 4; ++i) acc[rt][i] = zero4();
  #pragma unroll 1
  for (int ks = 0; ks < 16; ++ks){
    bf16x8 bfr[4];
    #pragma unroll
    for (int i = 0; i < 4; ++i){
      const int nt = w*4 + i;
      bfr[i] = __builtin_bit_cast(bf16x8,
          *(const u16x8*)(fB + (((size_t)ks * 32 + nt) * 64 + lane) * 8));
    }
    #pragma unroll
    for (int rt = 0; rt < 4; ++rt){
      bf16x8 af = __builtin_bit_cast(bf16x8,
          *(const u16x8*)&AS[(((rt*16 + ks)*4 + q)*16 + c)*8]);
      #pragma unroll
      for (int i = 0; i < 4; ++i)
        acc[rt][i] = MFMA16x16(af, bfr[i], acc[rt][i]);
    }
  }
  __syncthreads();
  #pragma unroll
  for (int rt = 0; rt < 4; ++rt)
    #pragma unroll
    for (int i = 0; i < 4; ++i){
      const int cl = (w*4 + i)*16 + c;
      const int ks2 = cl >> 5, qq = (cl >> 3) & 3, j = cl & 7;
      #pragma unroll
      for (int r = 0; r < 4; ++r){
        const int m = q*4 + r;
        float v = acc[rt][i][r];
        v = fmaxf(v, 0.1f * v);
        AS[(((rt*16 + ks2)*4 + qq)*16 + m)*8 + j] =
            (cl < 500) ? f2bf(v) : ((cl == 511) ? (u16)0x3F80 : (u16)0);
      }
    }
  __syncthreads();

  // ---- stage 3 ----
  if (mode == 0){
    if (w < 4){
      const int rt3 = w;
      f32x4 a3 = zero4();
      #pragma unroll 1
      for (int ks = 0; ks < 16; ++ks){
        bf16x8 af = __builtin_bit_cast(bf16x8,
            *(const u16x8*)&AS[(((rt3*16 + ks)*4 + q)*16 + c)*8]);
        bf16x8 bf = __builtin_bit_cast(bf16x8,
            *(const u16x8*)(f3 + (((size_t)ks * 64) + lane) * 8));
        a3 = MFMA16x16(af, bf, a3);
      }
      if (c < 6){
        #pragma unroll
        for (int r = 0; r < 4; ++r){
          const size_t row = rowbase + rt3*16 + q*4 + r;   // = b*100 + t
          const int tt = (int)(row % 100);
          const int bb = (int)(row / 100);
          o0[((size_t)tt*512 + bb)*8 + c] = a3[r];         // time-major HM
        }
      }
    }
  } else {
    const int rt3 = w & 3, hh = w >> 2;
    f32x4 a3[3];
    #pragma unroll
    for (int ii = 0; ii < 3; ++ii) a3[ii] = zero4();
    #pragma unroll 1
    for (int ks = 0; ks < 16; ++ks){
      bf16x8 af = __builtin_bit_cast(bf16x8,
          *(const u16x8*)&AS[(((rt3*16 + ks)*4 + q)*16 + c)*8]);
      #pragma unroll
      for (int ii = 0; ii < 3; ++ii){
        const int nt = hh*3 + ii;
        bf16x8 bf = __builtin_bit_cast(bf16x8,
            *(const u16x8*)(f3 + (((size_t)ks * 6 + nt) * 64 + lane) * 8));
        a3[ii] = MFMA16x16(af, bf, a3[ii]);
      }
    }
    #pragma unroll
    for (int ii = 0; ii < 3; ++ii){
      const int cc = (hh*3 + ii)*16 + c;
      const int grp = cc / 48;
      const int cl = cc - grp * 48;
      if (cl < 38){
        #pragma unroll
        for (int r = 0; r < 4; ++r){
          const size_t row = rowbase + rt3*16 + q*4 + r;
          if (grp == 0) o0[row*38 + cl] = a3[ii][r];
          else          o1[row*38 + cl] = fast_softplus(a3[ii][r]) + 1e-4f;
        }
      }
    }
  }
}

// ---------------------------------------------------------------------------
// Sequential latent scan: only the 3x3 z-feedback part (h-part precomputed).
// hmT is TIME-MAJOR [t][512][8]; depth-2 register prefetch; NT stores.
// ---------------------------------------------------------------------------
__global__ void scan_kernel(const float* __restrict__ hmT, const float* __restrict__ eps,
                            const float* __restrict__ zmW, const float* __restrict__ zsW,
                            float* __restrict__ zgen, float* __restrict__ zmu,
                            float* __restrict__ zstd)
{
  int b = blockIdx.x * blockDim.x + threadIdx.x;
  if (b >= 512) return;
  float Wm[3][3], Ws[3][3];
  #pragma unroll
  for (int j = 0; j < 3; ++j)
    #pragma unroll
    for (int k = 0; k < 3; ++k){
      Wm[j][k] = zmW[j * 503 + 500 + k];
      Ws[j][k] = zsW[j * 503 + 500 + k];
    }
  // slot A = even t, slot B = odd t
  f32x4 hA0, hA1, hB0, hB1;
  float eA0, eA1, eA2, eB0, eB1, eB2;
  hA0 = *(const f32x4*)(hmT + ((size_t)0*512 + b)*8);
  hA1 = *(const f32x4*)(hmT + ((size_t)0*512 + b)*8 + 4);
  hB0 = *(const f32x4*)(hmT + ((size_t)1*512 + b)*8);
  hB1 = *(const f32x4*)(hmT + ((size_t)1*512 + b)*8 + 4);
  {
    const float* e0p = eps + ((size_t)b*100 + 0)*3;
    const float* e1p = eps + ((size_t)b*100 + 1)*3;
    eA0 = e0p[0]; eA1 = e0p[1]; eA2 = e0p[2];
    eB0 = e1p[0]; eB1 = e1p[1]; eB2 = e1p[2];
  }
  float z0 = 0.f, z1 = 0.f, z2 = 0.f;
  #pragma unroll 1
  for (int t = 0; t < 100; t += 2){
    // ---- body 1: step t (slot A) ----
    {
      float h0 = hA0[0], h1 = hA0[1], h2 = hA0[2];
      float h3 = hA0[3], h4 = hA1[0], h5 = hA1[1];
      float e0 = eA0, e1 = eA1, e2 = eA2;
      if (t + 2 < 100){                      // prefetch t+2 into A
        hA0 = *(const f32x4*)(hmT + ((size_t)(t+2)*512 + b)*8);
        hA1 = *(const f32x4*)(hmT + ((size_t)(t+2)*512 + b)*8 + 4);
        const float* ep = eps + ((size_t)b*100 + (t+2))*3;
        eA0 = ep[0]; eA1 = ep[1]; eA2 = ep[2];
      }
      size_t row = (size_t)b*100 + t;
      float m0 = h0 + Wm[0][0]*z0 + Wm[0][1]*z1 + Wm[0][2]*z2;
      float m1 = h1 + Wm[1][0]*z0 + Wm[1][1]*z1 + Wm[1][2]*z2;
      float m2 = h2 + Wm[2][0]*z0 + Wm[2][1]*z1 + Wm[2][2]*z2;
      float s0 = fast_softplus(h3 + Ws[0][0]*z0 + Ws[0][1]*z1 + Ws[0][2]*z2) + 1e-4f;
      float s1 = fast_softplus(h4 + Ws[1][0]*z0 + Ws[1][1]*z1 + Ws[1][2]*z2) + 1e-4f;
      float s2 = fast_softplus(h5 + Ws[2][0]*z0 + Ws[2][1]*z1 + Ws[2][2]*z2) + 1e-4f;
      z0 = m0 + s0*e0; z1 = m1 + s1*e1; z2 = m2 + s2*e2;
      __builtin_nontemporal_store(z0, zgen + row*3 + 0);
      __builtin_nontemporal_store(z1, zgen + row*3 + 1);
      __builtin_nontemporal_store(z2, zgen + row*3 + 2);
      __builtin_nontemporal_store(m0, zmu  + row*3 + 0);
      __builtin_nontemporal_store(m1, zmu  + row*3 + 1);
      __builtin_nontemporal_store(m2, zmu  + row*3 + 2);
      __builtin_nontemporal_store(s0, zstd + row*3 + 0);
      __builtin_nontemporal_store(s1, zstd + row*3 + 1);
      __builtin_nontemporal_store(s2, zstd + row*3 + 2);
    }
    // ---- body 2: step t+1 (slot B) ----
    {
      float h0 = hB0[0], h1 = hB0[1], h2 = hB0[2];
      float h3 = hB0[3], h4 = hB1[0], h5 = hB1[1];
      float e0 = eB0, e1 = eB1, e2 = eB2;
      if (t + 3 < 100){                      // prefetch t+3 into B
        hB0 = *(const f32x4*)(hmT + ((size_t)(t+3)*512 + b)*8);
        hB1 = *(const f32x4*)(hmT + ((size_t)(t+3)*512 + b)*8 + 4);
        const float* ep = eps + ((size_t)b*100 + (t+3))*3;
        eB0 = ep[0]; eB1 = ep[1]; eB2 = ep[2];
      }
      size_t row = (size_t)b*100 + t + 1;
      float m0 = h0 + Wm[0][0]*z0 + Wm[0][1]*z1 + Wm[0][2]*z2;
      float m1 = h1 + Wm[1][0]*z0 + Wm[1][1]*z1 + Wm[1][2]*z2;
      float m2 = h2 + Wm[2][0]*z0 + Wm[2][1]*z1 + Wm[2][2]*z2;
      float s0 = fast_softplus(h3 + Ws[0][0]*z0 + Ws[0][1]*z1 + Ws[0][2]*z2) + 1e-4f;
      float s1 = fast_softplus(h4 + Ws[1][0]*z0 + Ws[1][1]*z1 + Ws[1][2]*z2) + 1e-4f;
      float s2 = fast_softplus(h5 + Ws[2][0]*z0 + Ws[2][1]*z1 + Ws[2][2]*z2) + 1e-4f;
      z0 = m0 + s0*e0; z1 = m1 + s1*e1; z2 = m2 + s2*e2;
      __builtin_nontemporal_store(z0, zgen + row*3 + 0);
      __builtin_nontemporal_store(z1, zgen + row*3 + 1);
      __builtin_nontemporal_store(z2, zgen + row*3 + 2);
      __builtin_nontemporal_store(m0, zmu  + row*3 + 0);
      __builtin_nontemporal_store(m1, zmu  + row*3 + 1);
      __builtin_nontemporal_store(m2, zmu  + row*3 + 2);
      __builtin_nontemporal_store(s0, zstd + row*3 + 0);
      __builtin_nontemporal_store(s1, zstd + row*3 + 1);
      __builtin_nontemporal_store(s2, zstd + row*3 + 2);
    }
  }
}

// ---------------------------------------------------------------------------
// Planar flow (parallel over 51200); also emits packed bf16 z for dec GRU.
// ---------------------------------------------------------------------------
__global__ void flow_kernel(const float* __restrict__ zgen, const float* __restrict__ fp,
                            float* __restrict__ zfin, float* __restrict__ ldj,
                            u16* __restrict__ zf16)
{
  int idx = blockIdx.x * blockDim.x + threadIdx.x;
  if (idx >= 51200) return;
  float z0 = zgen[idx*3+0], z1 = zgen[idx*3+1], z2 = zgen[idx*3+2];
  float ld = 0.f;
  #pragma unroll 1
  for (int l = 0; l < 20; ++l){
    const float* p = fp + l * 8;
    float lin = z0*p[0] + z1*p[1] + z2*p[2] + p[3];
    float tt = fast_tanh(lin);
    z0 += p[4]*tt; z1 += p[5]*tt; z2 += p[6]*tt;
    float det = 1.f + (1.f - tt*tt) * p[7];
    ld += __logf(fabsf(det) + 1e-7f);
  }
  zfin[idx*3+0] = z0; zfin[idx*3+1] = z1; zfin[idx*3+2] = z2;
  ldj[idx] = ld;
  u16x4 o; o[0] = f2bf(z0); o[1] = f2bf(z1); o[2] = f2bf(z2); o[3] = 0x3F80;
  *(u16x4*)(zf16 + (size_t)idx * 4) = o;
}

// ---------------------------------------------------------------------------
extern "C" void kernel_launch(void* const* d_in, const int* in_sizes, int n_in,
                              void* d_out, int out_size, void* d_ws, size_t ws_size,
                              hipStream_t stream)
{
  const float* x       = (const float*)d_in[0];
  const float* eps     = (const float*)d_in[1];
  const float* enc_Wih = (const float*)d_in[2];
  const float* enc_Whh = (const float*)d_in[3];
  const float* enc_bih = (const float*)d_in[4];
  const float* enc_bhh = (const float*)d_in[5];
  const float* enc_W1  = (const float*)d_in[6];
  const float* enc_b1  = (const float*)d_in[7];
  const float* enc_W2  = (const float*)d_in[8];
  const float* enc_b2  = (const float*)d_in[9];
  const float* zm_W    = (const float*)d_in[10];
  const float* zm_b    = (const float*)d_in[11];
  const float* zs_W    = (const float*)d_in[12];
  const float* zs_b    = (const float*)d_in[13];
  const float* flow_w  = (const float*)d_in[14];
  const float* flow_b  = (const float*)d_in[15];
  const float* flow_u  = (const float*)d_in[16];
  const float* dec_Wih = (const float*)d_in[17];
  const float* dec_Whh = (const float*)d_in[18];
  const float* dec_bih = (const float*)d_in[19];
  const float* dec_bhh = (const float*)d_in[20];
  const float* dec_W1  = (const float*)d_in[21];
  const float* dec_b1  = (const float*)d_in[22];
  const float* dec_W2  = (const float*)d_in[23];
  const float* dec_b2  = (const float*)d_in[24];
  const float* xm_W    = (const float*)d_in[25];
  const float* xm_b    = (const float*)d_in[26];
  const float* xs_W    = (const float*)d_in[27];
  const float* xs_b    = (const float*)d_in[28];
  (void)in_sizes; (void)n_in; (void)out_size; (void)ws_size;

  float* out    = (float*)d_out;
  float* r_mu   = out;                 // [512,100,38]
  float* r_std  = out + 1945600;       // [512,100,38]
  float* r_zgen = out + 3891200;       // [512,100,3]
  float* r_zfin = out + 4044800;       // [512,100,3]
  float* r_zmu  = out + 4198400;       // [512,100,3]
  float* r_zstd = out + 4352000;       // [512,100,3]
  float* r_ldj  = out + 4505600;       // [512,100,1]

  char* ws = (char*)d_ws;
  size_t off = 0;
  auto alloc = [&](size_t bytes)->char*{
    char* p = ws + off;
    off += (bytes + 255) & ~(size_t)255;
    return p;
  };
  u16* H1    = (u16*)alloc((size_t)51200*512*2);     // GRU hidden states
  u16* ENCF  = (u16*)alloc((size_t)16*96*512*2);
  u16* DECF  = (u16*)alloc((size_t)16*96*512*2);
  u16* EGIF  = (u16*)alloc((size_t)2*96*512*2);
  u16* PF0   = (u16*)alloc((size_t)16*32*512*2);
  u16* PF1   = (u16*)alloc((size_t)16*32*512*2);
  u16* PF2   = (u16*)alloc((size_t)16*32*512*2);
  u16* PF3   = (u16*)alloc((size_t)16*32*512*2);
  u16* ZFR   = (u16*)alloc((size_t)16*1*512*2);
  u16* HFR   = (u16*)alloc((size_t)16*6*512*2);
  float* FPP = (float*)alloc((size_t)20*8*4);
  float* HM  = (float*)alloc((size_t)51200*8*4);     // time-major [100][512][8]
  u16* ZF16  = (u16*)alloc((size_t)51200*4*2);
  u32* HBUF  = (u32*)alloc((size_t)32*2*16*512*2);   // h exchange (packed bf16 pairs)
  u32* CNT   = (u32*)alloc((size_t)2*32*128*4);      // 512 B/group counters, enc+dec

  build_all<<<10850,256,0,stream>>>(ENCF,DECF,EGIF,PF0,PF1,PF2,PF3,ZFR,HFR,FPP,CNT,
      enc_Whh,enc_bhh,enc_Wih,dec_Whh,dec_bhh,
      enc_W1,enc_b1,enc_W2,enc_b2,dec_W1,dec_b1,dec_W2,dec_b2,
      zm_W,zm_b,zs_W,zs_b,xm_W,xm_b,xs_W,xs_b,flow_w,flow_b,flow_u);

  // --- encoder (fused input-gates; per-wave detect) ---
  gru8_kernel<<<256,256,0,stream>>>(ENCF, EGIF, x, nullptr, nullptr, enc_bih,
                                    HBUF, H1, CNT);
  post_chain<<<800,512,0,stream>>>(H1, PF0, PF1, ZFR, HM, nullptr, 0);

  // --- latent scan + planar flow ---
  scan_kernel<<<2,256,0,stream>>>(HM, eps, zm_W, zs_W, r_zgen, r_zmu, r_zstd);
  flow_kernel<<<200,256,0,stream>>>(r_zgen, FPP, r_zfin, r_ldj, ZF16);

  // --- decoder (per-wave detect) ---
  gru8_kernel<<<256,256,0,stream>>>(DECF, nullptr, nullptr, (const u64*)ZF16,
                                    dec_Wih, dec_bih, HBUF, H1, CNT + 32*128);
  post_chain<<<800,512,0,stream>>>(H1, PF2, PF3, HFR, r_mu, r_std, 1);
}

// Round 15
// 1024.085 us; speedup vs baseline: 1.0280x; 1.0280x over previous
//
#include <hip/hip_runtime.h>

typedef unsigned short u16;
typedef unsigned int u32;
typedef unsigned long long u64;
typedef __bf16 bf16x8 __attribute__((ext_vector_type(8)));
typedef float f32x4 __attribute__((ext_vector_type(4)));
typedef u16 u16x8 __attribute__((ext_vector_type(8)));
typedef u16 u16x4 __attribute__((ext_vector_type(4)));
typedef u32 u32x4 __attribute__((ext_vector_type(4)));

#define MFMA16x16(a,b,c) __builtin_amdgcn_mfma_f32_16x16x32_bf16((a),(b),(c),0,0,0)

static __device__ __forceinline__ u16 f2bf(float f){
  u32 u = __builtin_bit_cast(u32, f);
  u += 0x7fffu + ((u >> 16) & 1u);
  return (u16)(u >> 16);
}
static __device__ __forceinline__ float bf2f(u16 h){
  u32 u = ((u32)h) << 16;
  return __builtin_bit_cast(float, u);
}
static __device__ __forceinline__ float fast_sigmoid(float x){
  return 1.f / (1.f + __expf(-x));
}
static __device__ __forceinline__ float fast_tanh(float x){
  float e = __expf(2.f * x);
  return 1.f - 2.f / (e + 1.f);
}
static __device__ __forceinline__ float fast_softplus(float x){
  return (x > 15.f) ? x : __logf(1.f + __expf(x));
}
static __device__ __forceinline__ f32x4 zero4(){
  f32x4 v; v[0]=0.f; v[1]=0.f; v[2]=0.f; v[3]=0.f; return v;
}
static __device__ __forceinline__ f32x4 splat4(float x){
  f32x4 v; v[0]=x; v[1]=x; v[2]=x; v[3]=x; return v;
}

// ---------------------------------------------------------------------------
// Weight swizzle into MFMA B-fragment order:
// dst[ks][nt][lane][j] = W[k = ks*32 + (lane>>4)*8 + j][ncol = nt*16 + (lane&15)]
// modes: 0 GRU hidden  2 post(500x500+b)  3 zW  4 heads  5 enc Wih
// ---------------------------------------------------------------------------
static __device__ __forceinline__ void build_one(
    u16* __restrict__ dst, int mode, int NT, int idx,
    const float* __restrict__ W0, const float* __restrict__ b0,
    const float* __restrict__ W1, const float* __restrict__ b1)
{
  int j    = idx & 7;
  int lane = (idx >> 3) & 63;
  int ntks = idx >> 9;
  int nt   = ntks % NT;
  int ks   = ntks / NT;
  int k    = ks * 32 + ((lane >> 4) << 3) + j;
  int ncol = (nt << 4) + (lane & 15);
  float v = 0.f;
  if (mode == 0){                         // GRU hidden: rows 0..499 Whh^T, 511 bhh
    int g = ncol >> 9;
    int jin = ncol & 511;
    if (jin < 500){
      int row = g * 500 + jin;
      if (k < 500) v = W0[row * 500 + k];
      else if (k == 511) v = b0[row];
    }
  } else if (mode == 2){                  // post: W0 [500][500], bias row 511
    if (ncol < 500){
      if (k < 500) v = W0[ncol * 500 + k];
      else if (k == 511) v = b0[ncol];
    }
  } else if (mode == 3){                  // zW: cols 0..2 zm (W0 [3][503]), 3..5 zs
    int c = ncol;
    if (c < 3){
      if (k < 500) v = W0[c * 503 + k];
      else if (k == 511) v = b0[c];
    } else if (c < 6){
      int cc = c - 3;
      if (k < 500) v = W1[cc * 503 + k];
      else if (k == 511) v = b1[cc];
    }
  } else if (mode == 4){                  // heads: cols 0..47 xm (<38), 48..95 xs
    int grp = ncol / 48;
    int cc  = ncol - grp * 48;
    if (grp < 2 && cc < 38){
      const float* W  = grp ? W1 : W0;
      const float* bb = grp ? b1 : b0;
      if (k < 500) v = W[cc * 500 + k];
      else if (k == 511) v = bb[cc];
    }
  } else {                                // mode 5: enc Wih [1500][38]
    int g = ncol >> 9;
    int jin = ncol & 511;
    if (jin < 500 && k < 38) v = W0[(g * 500 + jin) * 38 + k];
  }
  dst[idx] = f2bf(v);
}

// One launch for all weight prep + flow params + counter zeroing.
__global__ void build_all(
    u16* ENCF, u16* DECF, u16* EGIF, u16* PF0, u16* PF1, u16* PF2, u16* PF3,
    u16* ZFR, u16* HFR, float* FPP, u32* CNT,
    const float* enc_Whh, const float* enc_bhh, const float* enc_Wih,
    const float* dec_Whh, const float* dec_bhh,
    const float* enc_W1, const float* enc_b1, const float* enc_W2, const float* enc_b2,
    const float* dec_W1, const float* dec_b1, const float* dec_W2, const float* dec_b2,
    const float* zm_W, const float* zm_b, const float* zs_W, const float* zs_b,
    const float* xm_W, const float* xm_b, const float* xs_W, const float* xs_b,
    const float* flow_w, const float* flow_b, const float* flow_u)
{
  const int b = blockIdx.x, tid = threadIdx.x;
  if      (b < 3072)  build_one(ENCF,0,96,(b       )*256+tid, enc_Whh,enc_bhh,0,0);
  else if (b < 6144)  build_one(DECF,0,96,(b- 3072 )*256+tid, dec_Whh,dec_bhh,0,0);
  else if (b < 6528)  build_one(EGIF,5,96,(b- 6144 )*256+tid, enc_Wih,0,0,0);
  else if (b < 7552)  build_one(PF0 ,2,32,(b- 6528 )*256+tid, enc_W1,enc_b1,0,0);
  else if (b < 8576)  build_one(PF1 ,2,32,(b- 7552 )*256+tid, enc_W2,enc_b2,0,0);
  else if (b < 9600)  build_one(PF2 ,2,32,(b- 8576 )*256+tid, dec_W1,dec_b1,0,0);
  else if (b < 10624) build_one(PF3 ,2,32,(b- 9600 )*256+tid, dec_W2,dec_b2,0,0);
  else if (b < 10656) build_one(ZFR ,3, 1,(b-10624 )*256+tid, zm_W,zm_b,zs_W,zs_b);
  else if (b < 10848) build_one(HFR ,4, 6,(b-10656 )*256+tid, xm_W,xm_b,xs_W,xs_b);
  else if (b == 10848){
    if (tid < 20){
      int l = tid;
      float w0 = flow_w[l*3+0], w1 = flow_w[l*3+1], w2 = flow_w[l*3+2];
      float u0 = flow_u[l*3+0], u1 = flow_u[l*3+1], u2 = flow_u[l*3+2];
      float wu = w0*u0 + w1*u1 + w2*u2;
      float m  = -1.f + fast_softplus(wu);
      float ww = w0*w0 + w1*w1 + w2*w2 + 1e-7f;
      float sc = (m - wu) / ww;
      float uh0 = u0 + sc*w0, uh1 = u1 + sc*w1, uh2 = u2 + sc*w2;
      float uw  = uh0*w0 + uh1*w1 + uh2*w2;
      FPP[l*8+0]=w0; FPP[l*8+1]=w1; FPP[l*8+2]=w2; FPP[l*8+3]=flow_b[l];
      FPP[l*8+4]=uh0; FPP[l*8+5]=uh1; FPP[l*8+6]=uh2; FPP[l*8+7]=uw;
    }
  } else {
    for (int i = tid; i < 8192; i += 256) CNT[i] = 0;   // enc+dec counter arrays
  }
}

// ---------------------------------------------------------------------------
// GRU v19 = v18 (per-wave detect) + DOUBLE-BUFFERED LDS h-tile -> B3 removed.
// Plateau evidence (R9/R12/R13/R14 = 1035/1051/1037/1052): sync-latency
// floor, not mem/compute roofline. Last structural lever: B3 existed only
// because epilogue own-slice writes and MFMA tile reads shared one LDS
// buffer. The real tile is 16.6 KB (declared 83 KB is occupancy ballast),
// so double-buffer inside the same allocation: MFMA reads tile[t&1];
// epilogue writes h_{t+1} own-slice to tile[(t+1)&1]; next step's stage
// writes remote slices there (disjoint u32 ranges). Cross-wave orderings
// all covered by B2/B4 + in-block program order (audited pairwise).
// Steps now: per-wave detect + B2 (stage done) + B4 (vmcnt drain->signal).
// Protocol ledger: tagged R1-R3, XCD-L2 R6, K-split R11, residency pins
// R12/R13 all lost or null; counter protocol stands.
// ---------------------------------------------------------------------------
__global__ __launch_bounds__(256, 1) void gru8_kernel(
    const u16* __restrict__ frag, const u16* __restrict__ giw,
    const float* __restrict__ xsrc, const u64* __restrict__ zsrc,
    const float* __restrict__ Wih3, const float* __restrict__ bih3,
    u32* __restrict__ hbufbase, u16* __restrict__ hout, u32* __restrict__ cntbase)
{
  __shared__ u32 hstage[20800];             // 2 bufs x [16 rows][260]; tail = ballast
  __shared__ u16 xstage[1280];              // [2 slots][16 rows][40] (pads 38,39 = 0)
  const int tid  = threadIdx.x, lane = tid & 63;
  const int wv   = tid >> 6;                // 0..3
  const int q    = lane >> 4, c = lane & 15;
  const int gid  = blockIdx.x & 31, s = blockIdx.x >> 5;   // s = 0..7
  const int b0   = gid * 16;
  const int nt0  = s*4 + wv;                // 0..31
  const int col  = nt0*16 + c;
  u32* cnt = cntbase + gid * 128;           // 512 B stride
  u32* hb  = hbufbase + (size_t)gid * 8192; // 2 bufs x 16x256 u32
  const bool enc = (giw != nullptr);

  // --- hidden weights into VGPRs/AGPRs: 3 gates x 16 ks (held all steps) ---
  u16x8 wf[3][16];
  #pragma unroll
  for (int ks = 0; ks < 16; ++ks)
    #pragma unroll
    for (int g = 0; g < 3; ++g)
      wf[g][ks] = *(const u16x8*)(frag + (((size_t)ks*96 + g*32 + nt0)*64 + lane)*8);

  // --- encoder: Wih B-frags (2 ks x 3 gates) + per-thread biases +
  //     cooperative x-staging geometry (3 (row,k) pairs, constant over t) ---
  u16x8 wih[2][3];
  float bs0 = 0.f, bs1 = 0.f, bs2 = 0.f;
  int xr0=0, xk0=0, xr1=0, xk1=0, xr2=0, xk2=0;
  if (enc){
    #pragma unroll
    for (int ks = 0; ks < 2; ++ks)
      #pragma unroll
      for (int g = 0; g < 3; ++g)
        wih[ks][g] = *(const u16x8*)(giw + (((size_t)ks*96 + g*32 + nt0)*64 + lane)*8);
    if (col < 500){
      bs0 = bih3[col]; bs1 = bih3[500 + col]; bs2 = bih3[1000 + col];
    }
    xr0 = tid / 38;         xk0 = tid - xr0*38;          // e = tid       (0..255)
    int e1 = tid + 256;     xr1 = e1 / 38; xk1 = e1 - xr1*38;   // 256..511
    if (tid < 96){ int e2 = tid + 512; xr2 = e2 / 38; xk2 = e2 - xr2*38; } // 512..607
  }

  // --- decoder-mode per-lane gi weights (z is rank 3) ---
  float wz[3][3] = {{0,0,0},{0,0,0},{0,0,0}}, wb[3] = {0,0,0};
  if (!enc && col < 500){
    #pragma unroll
    for (int g = 0; g < 3; ++g){
      #pragma unroll
      for (int k = 0; k < 3; ++k) wz[g][k] = Wih3[(g*500 + col)*3 + k];
      wb[g] = bih3[g*500 + col];
    }
  }

  // --- staging geometry: thread stages 1 u64 per remote slice ---
  const int srow = tid >> 4;                // 0..15
  const int spos = (tid & 15) * 2;          // u32 offset within 32-u32 slice row

  float hold[4] = {0.f, 0.f, 0.f, 0.f};
  u64 zv[4];
  float xf0 = 0.f, xf1 = 0.f, xf2 = 0.f;    // next-step x floats (enc)
  {
    // h0 = 0 (+ col511 = 1.0): own LDS copy (buffer 0) + IF copy for remotes
    u32 me = (col == 511) ? 0x3F80u : 0u;
    u32 pr = __shfl_xor(me, 1, 64);
    if (!(c & 1)){
      u32 val = me | (pr << 16);
      #pragma unroll
      for (int r = 0; r < 4; ++r){
        hstage[(q*4+r)*260 + (col>>1)] = val;
        __hip_atomic_store(hb + (q*4+r)*256 + (col>>1), val,
                           __ATOMIC_RELAXED, __HIP_MEMORY_SCOPE_AGENT);
      }
    }
    // prime inputs for t=0
    if (enc){
      // zero pad columns 38,39 of both slots
      if (tid < 64){
        int slot = tid >> 5, r = tid & 15, p = (tid >> 4) & 1;
        xstage[slot*640 + r*40 + 38 + p] = 0;
      }
      float v0 = xsrc[((size_t)(b0 + xr0)*100 + 0)*38 + xk0];
      float v1 = xsrc[((size_t)(b0 + xr1)*100 + 0)*38 + xk1];
      xstage[xr0*40 + xk0] = f2bf(v0);
      xstage[xr1*40 + xk1] = f2bf(v1);
      if (tid < 96){
        float v2 = xsrc[((size_t)(b0 + xr2)*100 + 0)*38 + xk2];
        xstage[xr2*40 + xk2] = f2bf(v2);
      }
    } else {
      #pragma unroll
      for (int r = 0; r < 4; ++r)
        zv[r] = zsrc[(size_t)(b0 + q*4 + r)*100 + 0];
    }
  }
  __syncthreads();                          // drains vmcnt(0): h0 stores acked at IF
  if (tid == 0)
    __hip_atomic_fetch_add(cnt, 1u, __ATOMIC_RELAXED, __HIP_MEMORY_SCOPE_AGENT);

  #pragma unroll 1
  for (int t = 0; t < 100; ++t){
    const int cb = (t & 1) * 4160;          // current h-tile buffer
    const int nb = ((t+1) & 1) * 4160;      // next h-tile buffer

    // --- per-wave detect: lane 0 spins; wave reconverges (no B1 barrier) ---
    if (lane == 0){
      const u32 target = 8u*(u32)(t+1);
      int guard = 0;
      while (__hip_atomic_load(cnt, __ATOMIC_RELAXED, __HIP_MEMORY_SCOPE_AGENT) < target){
        if (++guard > (1<<24)) break;       // hang-breaker
      }
    }

    // --- stage 7 remote slices into tile[cb] (overlapped u64 loads) ---
    {
      const u64* src = (const u64*)(hb + (t & 1)*4096);
      u64 sv[7];
      #pragma unroll
      for (int r = 0; r < 7; ++r){
        const int rs = (s + 1 + r) & 7;
        sv[r] = __hip_atomic_load(src + srow*128 + rs*16 + (tid & 15),
                                  __ATOMIC_RELAXED, __HIP_MEMORY_SCOPE_AGENT);
      }
      // issue next-step x loads (coalesced; consumed in epilogue -> RT hidden)
      if (enc && t < 99){
        xf0 = xsrc[((size_t)(b0 + xr0)*100 + (t+1))*38 + xk0];
        xf1 = xsrc[((size_t)(b0 + xr1)*100 + (t+1))*38 + xk1];
        if (tid < 96) xf2 = xsrc[((size_t)(b0 + xr2)*100 + (t+1))*38 + xk2];
      }
      #pragma unroll
      for (int r = 0; r < 7; ++r){
        const int rs = (s + 1 + r) & 7;
        *(u64*)&hstage[cb + srow*260 + rs*32 + spos] = sv[r];
      }
    }
    __syncthreads();                        // B2: full h_t tile[cb] in LDS

    // --- accumulators: enc seeds r/z/n with fused gi (A-frags from LDS) ---
    f32x4 acc0, acc1, acc2, gN;
    if (enc){
      const int slot = t & 1;
      bf16x8 ax0 = *(const bf16x8*)&xstage[slot*640 + c*40 + q*8];
      u16x8 z8 = {0,0,0,0,0,0,0,0};
      bf16x8 ax1 = __builtin_bit_cast(bf16x8, z8);
      if (q == 0) ax1 = *(const bf16x8*)&xstage[slot*640 + c*40 + 32];
      acc0 = splat4(bs0);
      acc0 = MFMA16x16(ax0, __builtin_bit_cast(bf16x8, wih[0][0]), acc0);
      acc0 = MFMA16x16(ax1, __builtin_bit_cast(bf16x8, wih[1][0]), acc0);
      acc1 = splat4(bs1);
      acc1 = MFMA16x16(ax0, __builtin_bit_cast(bf16x8, wih[0][1]), acc1);
      acc1 = MFMA16x16(ax1, __builtin_bit_cast(bf16x8, wih[1][1]), acc1);
      gN   = splat4(bs2);
      gN   = MFMA16x16(ax0, __builtin_bit_cast(bf16x8, wih[0][2]), gN);
      gN   = MFMA16x16(ax1, __builtin_bit_cast(bf16x8, wih[1][2]), gN);
      acc2 = zero4();
    } else {
      acc0 = zero4(); acc1 = zero4(); acc2 = zero4(); gN = zero4();
    }
    #pragma unroll
    for (int ks = 0; ks < 16; ++ks){
      bf16x8 af = *(const bf16x8*)&hstage[cb + c*260 + ks*16 + q*4];
      acc0 = MFMA16x16(af, __builtin_bit_cast(bf16x8, wf[0][ks]), acc0);
      acc1 = MFMA16x16(af, __builtin_bit_cast(bf16x8, wf[1][ks]), acc1);
      acc2 = MFMA16x16(af, __builtin_bit_cast(bf16x8, wf[2][ks]), acc2);
    }
    // NO B3: epilogue writes target tile[nb] (disjoint from tile[cb] reads).

    // --- epilogue: write next x tile to LDS (visible after B4) ---
    if (enc && t < 99){
      const int ns = (t+1) & 1;
      xstage[ns*640 + xr0*40 + xk0] = f2bf(xf0);
      xstage[ns*640 + xr1*40 + xk1] = f2bf(xf1);
      if (tid < 96) xstage[ns*640 + xr2*40 + xk2] = f2bf(xf2);
    }

    u16 hvv[4];
    u32* nxt = hb + ((t+1) & 1)*4096;
    {
      #pragma unroll
      for (int r = 0; r < 4; ++r){
        float ar, az, gn;
        if (enc){
          ar = acc0[r]; az = acc1[r]; gn = gN[r];
        } else {
          float z0 = bf2f((u16)(zv[r]));
          float z1 = bf2f((u16)(zv[r] >> 16));
          float z2 = bf2f((u16)(zv[r] >> 32));
          ar = acc0[r] + z0*wz[0][0] + z1*wz[0][1] + z2*wz[0][2] + wb[0];
          az = acc1[r] + z0*wz[1][0] + z1*wz[1][1] + z2*wz[1][2] + wb[1];
          gn = z0*wz[2][0] + z1*wz[2][1] + z2*wz[2][2] + wb[2];
        }
        float an = acc2[r];
        float rr = fast_sigmoid(ar);
        float zz = fast_sigmoid(az);
        float nn = fast_tanh(gn + rr*an);
        float h  = (1.f - zz)*nn + zz*hold[r];
        hold[r] = h;
        u16 hv16 = (col < 500) ? f2bf(h) : ((col == 511) ? (u16)0x3F80 : (u16)0);
        hvv[r] = hv16;
        u32 me = hv16;
        u32 pr = __shfl_xor(me, 1, 64);
        if (!(c & 1)){
          u32 val = me | (pr << 16);
          hstage[nb + (q*4+r)*260 + (col>>1)] = val;  // own slice -> tile[nb]
          __hip_atomic_store(nxt + (q*4+r)*256 + (col>>1), val,
                             __ATOMIC_RELAXED, __HIP_MEMORY_SCOPE_AGENT);
        }
      }
    }
    __syncthreads();                        // B4: drains vmcnt -> stores at IF
    if (tid == 0)
      __hip_atomic_fetch_add(cnt, 1u, __ATOMIC_RELAXED, __HIP_MEMORY_SCOPE_AGENT);
    // off-critical-path: hout + next-input prefetch (dec)
    #pragma unroll
    for (int r = 0; r < 4; ++r)
      __builtin_nontemporal_store(hvv[r],
          hout + ((size_t)(b0 + q*4 + r)*100 + t)*512 + col);
    if (!enc && t < 99){
      #pragma unroll
      for (int r = 0; r < 4; ++r)
        zv[r] = zsrc[(size_t)(b0 + q*4 + r)*100 + (t+1)];
    }
  }
}

// ---------------------------------------------------------------------------
// Fused post-net chain v2 (unchanged from R9 — proven): B-frag register
// reuse via nt-quarter wave mapping; bit-exact vs v1.
// mode 0: hmT[t][512][8] = P2 @ ZFR   mode 1: heads (mu, softplus std).
// ---------------------------------------------------------------------------
__global__ __launch_bounds__(512, 4) void post_chain(
    const u16* __restrict__ A, const u16* __restrict__ fA,
    const u16* __restrict__ fB, const u16* __restrict__ f3,
    float* __restrict__ o0, float* __restrict__ o1, int mode)
{
  __shared__ u16 AS[32768];                 // [rt4][ks16][qq4][m16][j8]
  const int tid = threadIdx.x, lane = tid & 63, w = tid >> 6;
  const int q = lane >> 4, c = lane & 15;
  const size_t rowbase = (size_t)blockIdx.x * 64;

  // ---- stage 1: wave owns nt = w*4..w*4+3, loops all 4 row-tiles ----
  f32x4 acc[4][4];                          // [rt][i]
  #pragma unroll
  for (int rt = 0; rt < 4; ++rt)
    #pragma unroll
    for (int i = 0; i < 4; ++i) acc[rt][i] = zero4();
  #pragma unroll 1
  for (int ks = 0; ks < 16; ++ks){
    bf16x8 bfr[4];
    #pragma unroll
    for (int i = 0; i < 4; ++i){
      const int nt = w*4 + i;
      bfr[i] = __builtin_bit_cast(bf16x8,
          *(const u16x8*)(fA + (((size_t)ks * 32 + nt) * 64 + lane) * 8));
    }
    #pragma unroll
    for (int rt = 0; rt < 4; ++rt){
      bf16x8 af = __builtin_bit_cast(bf16x8,
          *(const u16x8*)(A + (rowbase + rt*16 + c) * 512 + ks * 32 + q * 8));
      #pragma unroll
      for (int i = 0; i < 4; ++i)
        acc[rt][i] = MFMA16x16(af, bfr[i], acc[rt][i]);
    }
  }
  #pragma unroll
  for (int rt = 0; rt < 4; ++rt)
    #pragma unroll
    for (int i = 0; i < 4; ++i){
      const int cl = (w*4 + i)*16 + c;
      const int ks2 = cl >> 5, qq = (cl >> 3) & 3, j = cl & 7;
      #pragma unroll
      for (int r = 0; r < 4; ++r){
        const int m = q*4 + r;
        float v = acc[rt][i][r];
        v = fmaxf(v, 0.1f * v);
        AS[(((rt*16 + ks2)*4 + qq)*16 + m)*8 + j] =
            (cl < 500) ? f2bf(v) : ((cl == 511) ? (u16)0x3F80 : (u16)0);
      }
    }
  __syncthreads();

  // ---- stage 2: same mapping, A from LDS ----
  #pragma unroll
  for (int rt = 0; rt < 4; ++rt)
    #pragma unroll
    for (int i = 0; i < 4; ++i) acc[rt][i] = zero4();
  #pragma unroll 1
  for (int ks = 0; ks < 16; ++ks){
    bf16x8 bfr[4];
    #pragma unroll
    for (int i = 0; i < 4; ++i){
      const int nt = w*4 + i;
      bfr[i] = __builtin_bit_cast(bf16x8,
          *(const u16x8*)(fB + (((size_t)ks * 32 + nt) * 64 + lane) * 8));
    }
    #pragma unroll
    for (int rt = 0; rt < 4; ++rt){
      bf16x8 af = __builtin_bit_cast(bf16x8,
          *(const u16x8*)&AS[(((rt*16 + ks)*4 + q)*16 + c)*8]);
      #pragma unroll
      for (int i = 0; i < 4; ++i)
        acc[rt][i] = MFMA16x16(af, bfr[i], acc[rt][i]);
    }
  }
  __syncthreads();
  #pragma unroll
  for (int rt = 0; rt < 4; ++rt)
    #pragma unroll
    for (int i = 0; i < 4; ++i){
      const int cl = (w*4 + i)*16 + c;
      const int ks2 = cl >> 5, qq = (cl >> 3) & 3, j = cl & 7;
      #pragma unroll
      for (int r = 0; r < 4; ++r){
        const int m = q*4 + r;
        float v = acc[rt][i][r];
        v = fmaxf(v, 0.1f * v);
        AS[(((rt*16 + ks2)*4 + qq)*16 + m)*8 + j] =
            (cl < 500) ? f2bf(v) : ((cl == 511) ? (u16)0x3F80 : (u16)0);
      }
    }
  __syncthreads();

  // ---- stage 3 ----
  if (mode == 0){
    if (w < 4){
      const int rt3 = w;
      f32x4 a3 = zero4();
      #pragma unroll 1
      for (int ks = 0; ks < 16; ++ks){
        bf16x8 af = __builtin_bit_cast(bf16x8,
            *(const u16x8*)&AS[(((rt3*16 + ks)*4 + q)*16 + c)*8]);
        bf16x8 bf = __builtin_bit_cast(bf16x8,
            *(const u16x8*)(f3 + (((size_t)ks * 64) + lane) * 8));
        a3 = MFMA16x16(af, bf, a3);
      }
      if (c < 6){
        #pragma unroll
        for (int r = 0; r < 4; ++r){
          const size_t row = rowbase + rt3*16 + q*4 + r;   // = b*100 + t
          const int tt = (int)(row % 100);
          const int bb = (int)(row / 100);
          o0[((size_t)tt*512 + bb)*8 + c] = a3[r];         // time-major HM
        }
      }
    }
  } else {
    const int rt3 = w & 3, hh = w >> 2;
    f32x4 a3[3];
    #pragma unroll
    for (int ii = 0; ii < 3; ++ii) a3[ii] = zero4();
    #pragma unroll 1
    for (int ks = 0; ks < 16; ++ks){
      bf16x8 af = __builtin_bit_cast(bf16x8,
          *(const u16x8*)&AS[(((rt3*16 + ks)*4 + q)*16 + c)*8]);
      #pragma unroll
      for (int ii = 0; ii < 3; ++ii){
        const int nt = hh*3 + ii;
        bf16x8 bf = __builtin_bit_cast(bf16x8,
            *(const u16x8*)(f3 + (((size_t)ks * 6 + nt) * 64 + lane) * 8));
        a3[ii] = MFMA16x16(af, bf, a3[ii]);
      }
    }
    #pragma unroll
    for (int ii = 0; ii < 3; ++ii){
      const int cc = (hh*3 + ii)*16 + c;
      const int grp = cc / 48;
      const int cl = cc - grp * 48;
      if (cl < 38){
        #pragma unroll
        for (int r = 0; r < 4; ++r){
          const size_t row = rowbase + rt3*16 + q*4 + r;
          if (grp == 0) o0[row*38 + cl] = a3[ii][r];
          else          o1[row*38 + cl] = fast_softplus(a3[ii][r]) + 1e-4f;
        }
      }
    }
  }
}

// ---------------------------------------------------------------------------
// Sequential latent scan: only the 3x3 z-feedback part (h-part precomputed).
// hmT is TIME-MAJOR [t][512][8]; depth-2 register prefetch; NT stores.
// ---------------------------------------------------------------------------
__global__ void scan_kernel(const float* __restrict__ hmT, const float* __restrict__ eps,
                            const float* __restrict__ zmW, const float* __restrict__ zsW,
                            float* __restrict__ zgen, float* __restrict__ zmu,
                            float* __restrict__ zstd)
{
  int b = blockIdx.x * blockDim.x + threadIdx.x;
  if (b >= 512) return;
  float Wm[3][3], Ws[3][3];
  #pragma unroll
  for (int j = 0; j < 3; ++j)
    #pragma unroll
    for (int k = 0; k < 3; ++k){
      Wm[j][k] = zmW[j * 503 + 500 + k];
      Ws[j][k] = zsW[j * 503 + 500 + k];
    }
  // slot A = even t, slot B = odd t
  f32x4 hA0, hA1, hB0, hB1;
  float eA0, eA1, eA2, eB0, eB1, eB2;
  hA0 = *(const f32x4*)(hmT + ((size_t)0*512 + b)*8);
  hA1 = *(const f32x4*)(hmT + ((size_t)0*512 + b)*8 + 4);
  hB0 = *(const f32x4*)(hmT + ((size_t)1*512 + b)*8);
  hB1 = *(const f32x4*)(hmT + ((size_t)1*512 + b)*8 + 4);
  {
    const float* e0p = eps + ((size_t)b*100 + 0)*3;
    const float* e1p = eps + ((size_t)b*100 + 1)*3;
    eA0 = e0p[0]; eA1 = e0p[1]; eA2 = e0p[2];
    eB0 = e1p[0]; eB1 = e1p[1]; eB2 = e1p[2];
  }
  float z0 = 0.f, z1 = 0.f, z2 = 0.f;
  #pragma unroll 1
  for (int t = 0; t < 100; t += 2){
    // ---- body 1: step t (slot A) ----
    {
      float h0 = hA0[0], h1 = hA0[1], h2 = hA0[2];
      float h3 = hA0[3], h4 = hA1[0], h5 = hA1[1];
      float e0 = eA0, e1 = eA1, e2 = eA2;
      if (t + 2 < 100){                      // prefetch t+2 into A
        hA0 = *(const f32x4*)(hmT + ((size_t)(t+2)*512 + b)*8);
        hA1 = *(const f32x4*)(hmT + ((size_t)(t+2)*512 + b)*8 + 4);
        const float* ep = eps + ((size_t)b*100 + (t+2))*3;
        eA0 = ep[0]; eA1 = ep[1]; eA2 = ep[2];
      }
      size_t row = (size_t)b*100 + t;
      float m0 = h0 + Wm[0][0]*z0 + Wm[0][1]*z1 + Wm[0][2]*z2;
      float m1 = h1 + Wm[1][0]*z0 + Wm[1][1]*z1 + Wm[1][2]*z2;
      float m2 = h2 + Wm[2][0]*z0 + Wm[2][1]*z1 + Wm[2][2]*z2;
      float s0 = fast_softplus(h3 + Ws[0][0]*z0 + Ws[0][1]*z1 + Ws[0][2]*z2) + 1e-4f;
      float s1 = fast_softplus(h4 + Ws[1][0]*z0 + Ws[1][1]*z1 + Ws[1][2]*z2) + 1e-4f;
      float s2 = fast_softplus(h5 + Ws[2][0]*z0 + Ws[2][1]*z1 + Ws[2][2]*z2) + 1e-4f;
      z0 = m0 + s0*e0; z1 = m1 + s1*e1; z2 = m2 + s2*e2;
      __builtin_nontemporal_store(z0, zgen + row*3 + 0);
      __builtin_nontemporal_store(z1, zgen + row*3 + 1);
      __builtin_nontemporal_store(z2, zgen + row*3 + 2);
      __builtin_nontemporal_store(m0, zmu  + row*3 + 0);
      __builtin_nontemporal_store(m1, zmu  + row*3 + 1);
      __builtin_nontemporal_store(m2, zmu  + row*3 + 2);
      __builtin_nontemporal_store(s0, zstd + row*3 + 0);
      __builtin_nontemporal_store(s1, zstd + row*3 + 1);
      __builtin_nontemporal_store(s2, zstd + row*3 + 2);
    }
    // ---- body 2: step t+1 (slot B) ----
    {
      float h0 = hB0[0], h1 = hB0[1], h2 = hB0[2];
      float h3 = hB0[3], h4 = hB1[0], h5 = hB1[1];
      float e0 = eB0, e1 = eB1, e2 = eB2;
      if (t + 3 < 100){                      // prefetch t+3 into B
        hB0 = *(const f32x4*)(hmT + ((size_t)(t+3)*512 + b)*8);
        hB1 = *(const f32x4*)(hmT + ((size_t)(t+3)*512 + b)*8 + 4);
        const float* ep = eps + ((size_t)b*100 + (t+3))*3;
        eB0 = ep[0]; eB1 = ep[1]; eB2 = ep[2];
      }
      size_t row = (size_t)b*100 + t + 1;
      float m0 = h0 + Wm[0][0]*z0 + Wm[0][1]*z1 + Wm[0][2]*z2;
      float m1 = h1 + Wm[1][0]*z0 + Wm[1][1]*z1 + Wm[1][2]*z2;
      float m2 = h2 + Wm[2][0]*z0 + Wm[2][1]*z1 + Wm[2][2]*z2;
      float s0 = fast_softplus(h3 + Ws[0][0]*z0 + Ws[0][1]*z1 + Ws[0][2]*z2) + 1e-4f;
      float s1 = fast_softplus(h4 + Ws[1][0]*z0 + Ws[1][1]*z1 + Ws[1][2]*z2) + 1e-4f;
      float s2 = fast_softplus(h5 + Ws[2][0]*z0 + Ws[2][1]*z1 + Ws[2][2]*z2) + 1e-4f;
      z0 = m0 + s0*e0; z1 = m1 + s1*e1; z2 = m2 + s2*e2;
      __builtin_nontemporal_store(z0, zgen + row*3 + 0);
      __builtin_nontemporal_store(z1, zgen + row*3 + 1);
      __builtin_nontemporal_store(z2, zgen + row*3 + 2);
      __builtin_nontemporal_store(m0, zmu  + row*3 + 0);
      __builtin_nontemporal_store(m1, zmu  + row*3 + 1);
      __builtin_nontemporal_store(m2, zmu  + row*3 + 2);
      __builtin_nontemporal_store(s0, zstd + row*3 + 0);
      __builtin_nontemporal_store(s1, zstd + row*3 + 1);
      __builtin_nontemporal_store(s2, zstd + row*3 + 2);
    }
  }
}

// ---------------------------------------------------------------------------
// Planar flow (parallel over 51200); also emits packed bf16 z for dec GRU.
// ---------------------------------------------------------------------------
__global__ void flow_kernel(const float* __restrict__ zgen, const float* __restrict__ fp,
                            float* __restrict__ zfin, float* __restrict__ ldj,
                            u16* __restrict__ zf16)
{
  int idx = blockIdx.x * blockDim.x + threadIdx.x;
  if (idx >= 51200) return;
  float z0 = zgen[idx*3+0], z1 = zgen[idx*3+1], z2 = zgen[idx*3+2];
  float ld = 0.f;
  #pragma unroll 1
  for (int l = 0; l < 20; ++l){
    const float* p = fp + l * 8;
    float lin = z0*p[0] + z1*p[1] + z2*p[2] + p[3];
    float tt = fast_tanh(lin);
    z0 += p[4]*tt; z1 += p[5]*tt; z2 += p[6]*tt;
    float det = 1.f + (1.f - tt*tt) * p[7];
    ld += __logf(fabsf(det) + 1e-7f);
  }
  zfin[idx*3+0] = z0; zfin[idx*3+1] = z1; zfin[idx*3+2] = z2;
  ldj[idx] = ld;
  u16x4 o; o[0] = f2bf(z0); o[1] = f2bf(z1); o[2] = f2bf(z2); o[3] = 0x3F80;
  *(u16x4*)(zf16 + (size_t)idx * 4) = o;
}

// ---------------------------------------------------------------------------
extern "C" void kernel_launch(void* const* d_in, const int* in_sizes, int n_in,
                              void* d_out, int out_size, void* d_ws, size_t ws_size,
                              hipStream_t stream)
{
  const float* x       = (const float*)d_in[0];
  const float* eps     = (const float*)d_in[1];
  const float* enc_Wih = (const float*)d_in[2];
  const float* enc_Whh = (const float*)d_in[3];
  const float* enc_bih = (const float*)d_in[4];
  const float* enc_bhh = (const float*)d_in[5];
  const float* enc_W1  = (const float*)d_in[6];
  const float* enc_b1  = (const float*)d_in[7];
  const float* enc_W2  = (const float*)d_in[8];
  const float* enc_b2  = (const float*)d_in[9];
  const float* zm_W    = (const float*)d_in[10];
  const float* zm_b    = (const float*)d_in[11];
  const float* zs_W    = (const float*)d_in[12];
  const float* zs_b    = (const float*)d_in[13];
  const float* flow_w  = (const float*)d_in[14];
  const float* flow_b  = (const float*)d_in[15];
  const float* flow_u  = (const float*)d_in[16];
  const float* dec_Wih = (const float*)d_in[17];
  const float* dec_Whh = (const float*)d_in[18];
  const float* dec_bih = (const float*)d_in[19];
  const float* dec_bhh = (const float*)d_in[20];
  const float* dec_W1  = (const float*)d_in[21];
  const float* dec_b1  = (const float*)d_in[22];
  const float* dec_W2  = (const float*)d_in[23];
  const float* dec_b2  = (const float*)d_in[24];
  const float* xm_W    = (const float*)d_in[25];
  const float* xm_b    = (const float*)d_in[26];
  const float* xs_W    = (const float*)d_in[27];
  const float* xs_b    = (const float*)d_in[28];
  (void)in_sizes; (void)n_in; (void)out_size; (void)ws_size;

  float* out    = (float*)d_out;
  float* r_mu   = out;                 // [512,100,38]
  float* r_std  = out + 1945600;       // [512,100,38]
  float* r_zgen = out + 3891200;       // [512,100,3]
  float* r_zfin = out + 4044800;       // [512,100,3]
  float* r_zmu  = out + 4198400;       // [512,100,3]
  float* r_zstd = out + 4352000;       // [512,100,3]
  float* r_ldj  = out + 4505600;       // [512,100,1]

  char* ws = (char*)d_ws;
  size_t off = 0;
  auto alloc = [&](size_t bytes)->char*{
    char* p = ws + off;
    off += (bytes + 255) & ~(size_t)255;
    return p;
  };
  u16* H1    = (u16*)alloc((size_t)51200*512*2);     // GRU hidden states
  u16* ENCF  = (u16*)alloc((size_t)16*96*512*2);
  u16* DECF  = (u16*)alloc((size_t)16*96*512*2);
  u16* EGIF  = (u16*)alloc((size_t)2*96*512*2);
  u16* PF0   = (u16*)alloc((size_t)16*32*512*2);
  u16* PF1   = (u16*)alloc((size_t)16*32*512*2);
  u16* PF2   = (u16*)alloc((size_t)16*32*512*2);
  u16* PF3   = (u16*)alloc((size_t)16*32*512*2);
  u16* ZFR   = (u16*)alloc((size_t)16*1*512*2);
  u16* HFR   = (u16*)alloc((size_t)16*6*512*2);
  float* FPP = (float*)alloc((size_t)20*8*4);
  float* HM  = (float*)alloc((size_t)51200*8*4);     // time-major [100][512][8]
  u16* ZF16  = (u16*)alloc((size_t)51200*4*2);
  u32* HBUF  = (u32*)alloc((size_t)32*2*16*512*2);   // h exchange (packed bf16 pairs)
  u32* CNT   = (u32*)alloc((size_t)2*32*128*4);      // 512 B/group counters, enc+dec

  build_all<<<10850,256,0,stream>>>(ENCF,DECF,EGIF,PF0,PF1,PF2,PF3,ZFR,HFR,FPP,CNT,
      enc_Whh,enc_bhh,enc_Wih,dec_Whh,dec_bhh,
      enc_W1,enc_b1,enc_W2,enc_b2,dec_W1,dec_b1,dec_W2,dec_b2,
      zm_W,zm_b,zs_W,zs_b,xm_W,xm_b,xs_W,xs_b,flow_w,flow_b,flow_u);

  // --- encoder (fused input-gates; per-wave detect; dbuf h-tile) ---
  gru8_kernel<<<256,256,0,stream>>>(ENCF, EGIF, x, nullptr, nullptr, enc_bih,
                                    HBUF, H1, CNT);
  post_chain<<<800,512,0,stream>>>(H1, PF0, PF1, ZFR, HM, nullptr, 0);

  // --- latent scan + planar flow ---
  scan_kernel<<<2,256,0,stream>>>(HM, eps, zm_W, zs_W, r_zgen, r_zmu, r_zstd);
  flow_kernel<<<200,256,0,stream>>>(r_zgen, FPP, r_zfin, r_ldj, ZF16);

  // --- decoder (per-wave detect; dbuf h-tile) ---
  gru8_kernel<<<256,256,0,stream>>>(DECF, nullptr, nullptr, (const u64*)ZF16,
                                    dec_Wih, dec_bih, HBUF, H1, CNT + 32*128);
  post_chain<<<800,512,0,stream>>>(H1, PF2, PF3, HFR, r_mu, r_std, 1);
}